// Round 2
// baseline (76.482 us; speedup 1.0000x reference)
//
#include <hip/hip_runtime.h>
#include <math.h>

#define B_ROWS 8192
#define D_DIM 512
#define N_LABELS 256
#define TCAP 48            // partner rows staged per LDS tile
#define TSTRIDE 520        // bf16 elems per staged row (512+8 pad; %8==0 -> 16B align + bank spread)
#define N_OCT 8            // row blocks per group (16 rows each)
#define ROWS_PER_BLOCK 16

static __device__ __forceinline__ unsigned int f2bf(float f) {
    // round-to-nearest-even fp32 -> bf16 bits
    unsigned int u = __float_as_uint(f);
    return (u + 0x7FFFu + ((u >> 16) & 1u)) >> 16;
}
static __device__ __forceinline__ float bf_lo(unsigned int u) {
    return __uint_as_float(u << 16);
}
static __device__ __forceinline__ float bf_hi(unsigned int u) {
    return __uint_as_float(u & 0xFFFF0000u);
}

// ---------------- fused bucketing: one block per label ----------------
__global__ __launch_bounds__(256) void bucket_kernel(const int* __restrict__ Mx,
                                                     int* __restrict__ counts,
                                                     int* __restrict__ offsets,
                                                     int* __restrict__ bucket) {
    __shared__ int hist[N_LABELS];
    __shared__ int wsum[4];
    __shared__ int off_sh;
    const int tid   = threadIdx.x;
    const int label = blockIdx.x;

    hist[tid] = 0;
    __syncthreads();
    for (int i = tid; i < B_ROWS; i += 256) atomicAdd(&hist[Mx[i]], 1);
    __syncthreads();

    // offset for this label = sum of hist[0..label)
    int partial = (tid < label) ? hist[tid] : 0;
    partial += __shfl_xor(partial, 1, 64);
    partial += __shfl_xor(partial, 2, 64);
    partial += __shfl_xor(partial, 4, 64);
    partial += __shfl_xor(partial, 8, 64);
    partial += __shfl_xor(partial, 16, 64);
    partial += __shfl_xor(partial, 32, 64);
    if ((tid & 63) == 0) wsum[tid >> 6] = partial;
    __syncthreads();
    if (tid == 0) {
        const int off = wsum[0] + wsum[1] + wsum[2] + wsum[3];
        off_sh = off;
        offsets[label] = off;
        counts[label]  = hist[label];
    }
    __syncthreads();

    // deterministic scatter: wave 0, ballot rank
    if (tid < 64) {
        const int lane = tid;
        int pos = off_sh;
        const unsigned long long lower = (lane == 0) ? 0ull : ((1ull << lane) - 1ull);
        for (int base = 0; base < B_ROWS; base += 64) {
            const bool match = (Mx[base + lane] == label);
            const unsigned long long bal = __ballot(match);
            if (match) bucket[pos + __popcll(bal & lower)] = base + lane;
            pos += __popcll(bal);
        }
    }
}

// ---------------- main loss kernel ----------------
// Block = (group g, row-block o): 512 threads = 8 waves; each wave handles 2 rows
// (lanes 0-31 -> row A, lanes 32-63 -> row B). Group rows staged in LDS as bf16;
// each lane owns one partner j and accumulates the full 512-dim distance in a
// register, so only ONE 5-stage butterfly per row.
__global__ __launch_bounds__(512) void loss_kernel(const float* __restrict__ z,
                                                   const int* __restrict__ counts,
                                                   const int* __restrict__ offsets,
                                                   const int* __restrict__ bucket,
                                                   float* __restrict__ out) {
    __shared__ __align__(16) unsigned short tile[TCAP * TSTRIDE]; // 49,920 B
    __shared__ int ids[TCAP];

    const int g   = blockIdx.x;
    const int o   = blockIdx.y;
    const int cnt = counts[g];
    if (o * ROWS_PER_BLOCK >= cnt) return;
    const int off = offsets[g];

    const int tid  = threadIdx.x;
    const int wv   = tid >> 6;      // wave 0..7
    const int lane = tid & 63;
    const int h    = lane >> 5;     // half-wave
    const int jl   = lane & 31;     // lane within half

    const int n_rgen = (cnt + (N_OCT * ROWS_PER_BLOCK) - 1) / (N_OCT * ROWS_PER_BLOCK);

    for (int rg = 0; rg < n_rgen; ++rg) {
        const int r_idx   = o * ROWS_PER_BLOCK + wv * 2 + h + rg * (N_OCT * ROWS_PER_BLOCK);
        const bool rvalid = (r_idx < cnt);
        const int r_eff   = rvalid ? r_idx : 0;
        const int i_id    = bucket[off + r_eff];
        const float* __restrict__ abase = z + (size_t)i_id * D_DIM;

        float acc = 0.f;

        for (int tb = 0; tb < cnt; tb += TCAP) {
            const int cnt_t = min(TCAP, cnt - tb);

            // ---- stage cnt_t rows fp32 -> bf16 into LDS ----
            if (tid < cnt_t) ids[tid] = bucket[off + tb + tid];
            for (int c = tid; c < cnt_t * (D_DIM / 4); c += 512) {
                const int row = c >> 7;          // D_DIM/4 == 128
                const int col = c & 127;
                const int jid = bucket[off + tb + row];   // wave-uniform -> broadcast
                const float4 v = *(const float4*)(z + (size_t)jid * D_DIM + col * 4);
                uint2 p;
                p.x = f2bf(v.x) | (f2bf(v.y) << 16);
                p.y = f2bf(v.z) | (f2bf(v.w) << 16);
                *(uint2*)(&tile[row * TSTRIDE + col * 4]) = p;
            }
            __syncthreads();

            // ---- compute: lane-per-partner, tiles of 32 per half-wave ----
            const int njt = (cnt_t + 31) >> 5;
            for (int jt = 0; jt < njt; ++jt) {
                const int j_sub  = jt * 32 + jl;
                const bool jval  = (j_sub < cnt_t);
                const int j_eff  = jval ? j_sub : 0;
                const int j_id   = ids[j_eff];
                const unsigned short* __restrict__ bp = &tile[j_eff * TSTRIDE];

                float s = 0.f;
                #pragma unroll 4
                for (int d = 0; d < D_DIM; d += 8) {
                    const uint4  bv = *(const uint4*)(bp + d);           // 8 bf16 dims
                    const float4 a0 = *(const float4*)(abase + d);       // uniform line
                    const float4 a1 = *(const float4*)(abase + d + 4);
                    float t;
                    t = a0.x - bf_lo(bv.x); s += t * t;
                    t = a0.y - bf_hi(bv.x); s += t * t;
                    t = a0.z - bf_lo(bv.y); s += t * t;
                    t = a0.w - bf_hi(bv.y); s += t * t;
                    t = a1.x - bf_lo(bv.z); s += t * t;
                    t = a1.y - bf_hi(bv.z); s += t * t;
                    t = a1.z - bf_lo(bv.w); s += t * t;
                    t = a1.w - bf_hi(bv.w); s += t * t;
                }
                if (jval && rvalid && (j_id != i_id)) acc += sqrtf(s);
            }
            __syncthreads();   // before next tile overwrites LDS
        }

        // one butterfly per row (within each 32-lane half)
        acc += __shfl_xor(acc, 1, 64);
        acc += __shfl_xor(acc, 2, 64);
        acc += __shfl_xor(acc, 4, 64);
        acc += __shfl_xor(acc, 8, 64);
        acc += __shfl_xor(acc, 16, 64);

        if (rvalid && jl == 0) {
            out[i_id] = (cnt > 1) ? acc / (float)(cnt - 1) : 0.f;
        }
    }
}

// ---------------- launch ----------------
extern "C" void kernel_launch(void* const* d_in, const int* in_sizes, int n_in,
                              void* d_out, int out_size, void* d_ws, size_t ws_size,
                              hipStream_t stream) {
    const float* z  = (const float*)d_in[0];
    const int*   Mx = (const int*)d_in[1];
    float*       out = (float*)d_out;

    int* counts  = (int*)d_ws;              // [256]
    int* offsets = counts + N_LABELS;       // [256]
    int* bucket  = offsets + N_LABELS;      // [8192]

    bucket_kernel<<<N_LABELS, 256, 0, stream>>>(Mx, counts, offsets, bucket);

    dim3 grid(N_LABELS, N_OCT);
    loss_kernel<<<grid, 512, 0, stream>>>(z, counts, offsets, bucket, out);
}